// Round 2
// baseline (5041.187 us; speedup 1.0000x reference)
//
#include <hip/hip_runtime.h>
#include <stdint.h>

#define S_LEN 2048
#define BATCH 2
#define NH 16
#define NKV 4
#define HD 128
#define HID 2048
#define MROWS (BATCH * S_LEN)  // 4096

typedef unsigned short u16;
// Per guide §3 (compile-verified on gfx950): 8 bf16 held as short8 (4 VGPRs)
typedef __attribute__((ext_vector_type(8))) short frag_ab;
typedef __attribute__((ext_vector_type(4))) float frag_cd;

static __device__ __forceinline__ float bf2f(u16 v) {
    union { unsigned u; float f; } t; t.u = ((unsigned)v) << 16; return t.f;
}
static __device__ __forceinline__ u16 f2bf(float f) {
    union { float f; unsigned u; } t; t.f = f;
    unsigned r = t.u + 0x7fffu + ((t.u >> 16) & 1u);  // RNE
    return (u16)(r >> 16);
}

// ---------------- fp32 -> bf16 bulk convert ----------------
__global__ __launch_bounds__(256) void conv_f32_bf16(const float* __restrict__ src,
                                                     u16* __restrict__ dst, int n4) {
    int i = blockIdx.x * 256 + threadIdx.x;
    if (i >= n4) return;
    float4 v = ((const float4*)src)[i];
    ushort4 o;
    o.x = f2bf(v.x); o.y = f2bf(v.y); o.z = f2bf(v.z); o.w = f2bf(v.w);
    ((ushort4*)dst)[i] = o;
}

// ---------------- C = A (MxK) * B^T (B stored [N][K]), fp32 out ----------------
// 128x128 block tile, 4 waves each 64x64 (4x4 MFMA 16x16x32 bf16), BK=32.
__global__ __launch_bounds__(256) void gemm_bt(const u16* __restrict__ A, const u16* __restrict__ B,
                                               float* __restrict__ C, int M, int N, int K) {
    __shared__ u16 As[128 * 32];
    __shared__ u16 Bs[128 * 32];
    const int tid = threadIdx.x;
    const int wave = tid >> 6, lane = tid & 63;
    const int quad = lane >> 4, lr = lane & 15;
    const int wm = (wave & 1) * 64, wn = (wave >> 1) * 64;
    const long bm = (long)blockIdx.x * 128, bn = (long)blockIdx.y * 128;
    const int r0 = tid >> 2;          // 0..63
    const int c0 = (tid & 3) * 8;     // 0,8,16,24
    const u16* Ap = A + (bm + r0) * (long)K + c0;
    const u16* Bp = B + (bn + r0) * (long)K + c0;

    frag_cd acc[4][4];
#pragma unroll
    for (int i = 0; i < 4; i++)
#pragma unroll
        for (int j = 0; j < 4; j++) acc[i][j] = (frag_cd){0.f, 0.f, 0.f, 0.f};

    for (int k0 = 0; k0 < K; k0 += 32) {
        uint4 a0 = *(const uint4*)(Ap + k0);
        uint4 a1 = *(const uint4*)(Ap + (long)64 * K + k0);
        uint4 b0 = *(const uint4*)(Bp + k0);
        uint4 b1 = *(const uint4*)(Bp + (long)64 * K + k0);
        __syncthreads();
        *(uint4*)(As + r0 * 32 + c0) = a0;
        *(uint4*)(As + (r0 + 64) * 32 + c0) = a1;
        *(uint4*)(Bs + r0 * 32 + c0) = b0;
        *(uint4*)(Bs + (r0 + 64) * 32 + c0) = b1;
        __syncthreads();
        frag_ab af[4], bfr[4];
#pragma unroll
        for (int i = 0; i < 4; i++) af[i] = *(const frag_ab*)(As + (wm + i * 16 + lr) * 32 + quad * 8);
#pragma unroll
        for (int j = 0; j < 4; j++) bfr[j] = *(const frag_ab*)(Bs + (wn + j * 16 + lr) * 32 + quad * 8);
#pragma unroll
        for (int i = 0; i < 4; i++)
#pragma unroll
            for (int j = 0; j < 4; j++)
                acc[i][j] = __builtin_amdgcn_mfma_f32_16x16x32_bf16(af[i], bfr[j], acc[i][j], 0, 0, 0);
    }
    // C/D layout: col = lane&15, row = (lane>>4)*4 + reg   [measured m89/m91]
#pragma unroll
    for (int i = 0; i < 4; i++)
#pragma unroll
        for (int j = 0; j < 4; j++)
#pragma unroll
            for (int r = 0; r < 4; r++) {
                long row = bm + wm + i * 16 + quad * 4 + r;
                long col = bn + wn + j * 16 + lr;
                C[row * N + col] = acc[i][j][r];
            }
}

// ---------------- RMSNorm(head_dim) + RoPE, fp32 in -> bf16 out [b][h][s][d] ----------------
__global__ __launch_bounds__(256) void rope_norm(const float* __restrict__ src, u16* __restrict__ dst,
                                                 const float* __restrict__ nw, int nh) {
    const int m = blockIdx.x;                 // 0..4095 (b*S+s)
    const int wave = threadIdx.x >> 6, lane = threadIdx.x & 63;
    const int s = m & (S_LEN - 1), b = m >> 11;
    const int d0 = 2 * lane;
    const float w0 = nw[d0], w1 = nw[d0 + 1];
    const int i0 = d0 & 63;
    const float lnt_over = 13.122363377404328f / 64.f;  // ln(500000)/64
    float inv0 = expf(-(float)i0 * lnt_over);
    float inv1 = expf(-(float)(i0 + 1) * lnt_over);
    float c0 = cosf((float)s * inv0), sn0 = sinf((float)s * inv0);
    float c1 = cosf((float)s * inv1), sn1 = sinf((float)s * inv1);
    for (int h = wave; h < nh; h += 4) {
        float2 x = *(const float2*)(src + (long)m * (nh * HD) + h * HD + d0);
        float ss = x.x * x.x + x.y * x.y;
#pragma unroll
        for (int off = 1; off < 64; off <<= 1) ss += __shfl_xor(ss, off);
        float rs = rsqrtf(ss * (1.f / HD) + 1e-5f);
        float xn0 = x.x * rs * w0;
        float xn1 = x.y * rs * w1;
        float p0 = __shfl_xor(xn0, 32);
        float p1 = __shfl_xor(xn1, 32);
        float r0 = (lane < 32) ? -p0 : p0;   // rotate_half
        float r1 = (lane < 32) ? -p1 : p1;
        float y0 = xn0 * c0 + r0 * sn0;
        float y1 = xn1 * c1 + r1 * sn1;
        unsigned outw = (unsigned)f2bf(y0) | ((unsigned)f2bf(y1) << 16);
        *(unsigned*)(dst + (((long)(b * nh + h) * S_LEN + s) * HD + d0)) = outw;
    }
}

// ---------------- V: fp32 [m][kh*128+d] -> bf16 [b][kh][s][d] ----------------
__global__ __launch_bounds__(256) void pack_v(const float* __restrict__ src, u16* __restrict__ dst) {
    const int m = blockIdx.x;
    const int t = threadIdx.x;  // 0..255
    const int s = m & (S_LEN - 1), b = m >> 11;
    const int col = 2 * t;      // 0..510
    const int h = col >> 7, d = col & 127;
    float2 x = *(const float2*)(src + (long)m * (NKV * HD) + col);
    unsigned outw = (unsigned)f2bf(x.x) | ((unsigned)f2bf(x.y) << 16);
    *(unsigned*)(dst + (((long)(b * NKV + h) * S_LEN + s) * HD + d)) = outw;
}

// ---------------- causal GQA flash attention, one wave per (b,h,q) ----------------
__global__ __launch_bounds__(256) void attn_kernel(const u16* __restrict__ Q, const u16* __restrict__ K,
                                                   const u16* __restrict__ V, u16* __restrict__ O) {
    const int wid = blockIdx.x * 4 + (threadIdx.x >> 6);
    const int lane = threadIdx.x & 63;
    const int q = wid & (S_LEN - 1);
    const int h = (wid >> 11) & (NH - 1);
    const int b = wid >> 15;
    const int kh = h >> 2;  // groups = 4
    const float scale = 0.08838834764831845f;  // 1/sqrt(128)
    const u16* qp = Q + (((long)(b * NH + h) * S_LEN + q) * HD) + 2 * lane;
    float q0 = bf2f(qp[0]) * scale;
    float q1 = bf2f(qp[1]) * scale;
    const u16* kb = K + ((long)(b * NKV + kh) * S_LEN) * HD + 2 * lane;
    const u16* vb = V + ((long)(b * NKV + kh) * S_LEN) * HD + 2 * lane;
    float m_i = -INFINITY, l_i = 0.f, o0 = 0.f, o1 = 0.f;
    for (int j = 0; j <= q; j++) {
        unsigned kv = *(const unsigned*)(kb + (long)j * HD);
        float p = q0 * bf2f((u16)kv) + q1 * bf2f((u16)(kv >> 16));
#pragma unroll
        for (int off = 1; off < 64; off <<= 1) p += __shfl_xor(p, off);
        float mn = fmaxf(m_i, p);
        float alpha = __expf(m_i - mn);
        float wgt = __expf(p - mn);
        unsigned vv = *(const unsigned*)(vb + (long)j * HD);
        l_i = l_i * alpha + wgt;
        o0 = o0 * alpha + wgt * bf2f((u16)vv);
        o1 = o1 * alpha + wgt * bf2f((u16)(vv >> 16));
        m_i = mn;
    }
    float inv = 1.f / l_i;
    unsigned outw = (unsigned)f2bf(o0 * inv) | ((unsigned)f2bf(o1 * inv) << 16);
    const long mrow = (long)b * S_LEN + q;
    *(unsigned*)(O + mrow * (NH * HD) + h * HD + 2 * lane) = outw;
}

extern "C" void kernel_launch(void* const* d_in, const int* in_sizes, int n_in,
                              void* d_out, int out_size, void* d_ws, size_t ws_size,
                              hipStream_t stream) {
    const float* hs  = (const float*)d_in[0];
    const float* q_w = (const float*)d_in[1];
    const float* k_w = (const float*)d_in[2];
    const float* v_w = (const float*)d_in[3];
    const float* o_w = (const float*)d_in[4];
    const float* qnw = (const float*)d_in[5];
    const float* knw = (const float*)d_in[6];
    float* out = (float*)d_out;

    // Workspace layout (72 MiB total, all live ranges verified disjoint):
    //   [ 0,16M)  hs_bf   : hidden bf16; reused as attn-out bf16 after V gemm
    //   [16,24M)  wbuf    : weights bf16 (reused per GEMM)
    //   [24,56M)  gout    : fp32 GEMM out. Q gemm uses all 32 MiB; K/V gemms
    //                       use only [24,32M), so Kr/Vr live in its dead tail.
    //   [40,44M)  Kr      : bf16 [b][4][s][128] (4 MiB)
    //   [44,48M)  Vr      : bf16 [b][4][s][128] (4 MiB)
    //   [56,72M)  Qr      : bf16 [b][16][s][128] (16 MiB — round-1 bug: was
    //                       sized 8 MiB and collided with Kr/Vr, killing b=1)
    char* ws = (char*)d_ws;
    u16* hs_bf  = (u16*)(ws);
    u16* wbuf   = (u16*)(ws + (16ul << 20));
    float* gout = (float*)(ws + (24ul << 20));
    u16* Kr     = (u16*)(ws + (40ul << 20));
    u16* Vr     = (u16*)(ws + (44ul << 20));
    u16* Qr     = (u16*)(ws + (56ul << 20));
    (void)ws_size; (void)in_sizes; (void)n_in; (void)out_size;

    // hidden -> bf16
    conv_f32_bf16<<<(MROWS * HID / 4 + 255) / 256, 256, 0, stream>>>(hs, hs_bf, MROWS * HID / 4);

    // Q = hs @ q_w^T ; rmsnorm + rope
    conv_f32_bf16<<<(HID * HID / 4 + 255) / 256, 256, 0, stream>>>(q_w, wbuf, HID * HID / 4);
    dim3 gq(MROWS / 128, HID / 128);
    gemm_bt<<<gq, 256, 0, stream>>>(hs_bf, wbuf, gout, MROWS, HID, HID);
    rope_norm<<<MROWS, 256, 0, stream>>>(gout, Qr, qnw, NH);

    // K
    conv_f32_bf16<<<(NKV * HD * HID / 4 + 255) / 256, 256, 0, stream>>>(k_w, wbuf, NKV * HD * HID / 4);
    dim3 gk(MROWS / 128, (NKV * HD) / 128);
    gemm_bt<<<gk, 256, 0, stream>>>(hs_bf, wbuf, gout, MROWS, NKV * HD, HID);
    rope_norm<<<MROWS, 256, 0, stream>>>(gout, Kr, knw, NKV);

    // V
    conv_f32_bf16<<<(NKV * HD * HID / 4 + 255) / 256, 256, 0, stream>>>(v_w, wbuf, NKV * HD * HID / 4);
    gemm_bt<<<gk, 256, 0, stream>>>(hs_bf, wbuf, gout, MROWS, NKV * HD, HID);
    pack_v<<<MROWS, 256, 0, stream>>>(gout, Vr);

    // attention -> hs_bf (attn matrix [m][h*128+d] in bf16)
    attn_kernel<<<(BATCH * NH * S_LEN) / 4, 256, 0, stream>>>(Qr, Kr, Vr, hs_bf);

    // out = attn @ o_w^T
    conv_f32_bf16<<<(HID * HID / 4 + 255) / 256, 256, 0, stream>>>(o_w, wbuf, HID * HID / 4);
    gemm_bt<<<gq, 256, 0, stream>>>(hs_bf, wbuf, out, MROWS, HID, HID);
}

// Round 3
// 550.599 us; speedup vs baseline: 9.1558x; 9.1558x over previous
//
#include <hip/hip_runtime.h>
#include <stdint.h>

#define S_LEN 2048
#define BATCH 2
#define NH 16
#define NKV 4
#define HD 128
#define HID 2048
#define MROWS (BATCH * S_LEN)  // 4096

typedef unsigned short u16;
// Per guide §3 (compile-verified on gfx950): 8 bf16 held as short8 (4 VGPRs)
typedef __attribute__((ext_vector_type(8))) short frag_ab;
typedef __attribute__((ext_vector_type(4))) float frag_cd;

static __device__ __forceinline__ float bf2f(u16 v) {
    union { unsigned u; float f; } t; t.u = ((unsigned)v) << 16; return t.f;
}
static __device__ __forceinline__ u16 f2bf(float f) {
    union { float f; unsigned u; } t; t.f = f;
    unsigned r = t.u + 0x7fffu + ((t.u >> 16) & 1u);  // RNE
    return (u16)(r >> 16);
}

// ---------------- fp32 -> bf16 bulk convert ----------------
__global__ __launch_bounds__(256) void conv_f32_bf16(const float* __restrict__ src,
                                                     u16* __restrict__ dst, int n4) {
    int i = blockIdx.x * 256 + threadIdx.x;
    if (i >= n4) return;
    float4 v = ((const float4*)src)[i];
    ushort4 o;
    o.x = f2bf(v.x); o.y = f2bf(v.y); o.z = f2bf(v.z); o.w = f2bf(v.w);
    ((ushort4*)dst)[i] = o;
}

// ---------------- C = A (MxK) * B^T (B stored [N][K]), fp32 out ----------------
// 128x128 block tile, 4 waves each 64x64 (4x4 MFMA 16x16x32 bf16), BK=32.
__global__ __launch_bounds__(256) void gemm_bt(const u16* __restrict__ A, const u16* __restrict__ B,
                                               float* __restrict__ C, int M, int N, int K) {
    __shared__ u16 As[128 * 32];
    __shared__ u16 Bs[128 * 32];
    const int tid = threadIdx.x;
    const int wave = tid >> 6, lane = tid & 63;
    const int quad = lane >> 4, lr = lane & 15;
    const int wm = (wave & 1) * 64, wn = (wave >> 1) * 64;
    const long bm = (long)blockIdx.x * 128, bn = (long)blockIdx.y * 128;
    const int r0 = tid >> 2;          // 0..63
    const int c0 = (tid & 3) * 8;     // 0,8,16,24
    const u16* Ap = A + (bm + r0) * (long)K + c0;
    const u16* Bp = B + (bn + r0) * (long)K + c0;

    frag_cd acc[4][4];
#pragma unroll
    for (int i = 0; i < 4; i++)
#pragma unroll
        for (int j = 0; j < 4; j++) acc[i][j] = (frag_cd){0.f, 0.f, 0.f, 0.f};

    for (int k0 = 0; k0 < K; k0 += 32) {
        uint4 a0 = *(const uint4*)(Ap + k0);
        uint4 a1 = *(const uint4*)(Ap + (long)64 * K + k0);
        uint4 b0 = *(const uint4*)(Bp + k0);
        uint4 b1 = *(const uint4*)(Bp + (long)64 * K + k0);
        __syncthreads();
        *(uint4*)(As + r0 * 32 + c0) = a0;
        *(uint4*)(As + (r0 + 64) * 32 + c0) = a1;
        *(uint4*)(Bs + r0 * 32 + c0) = b0;
        *(uint4*)(Bs + (r0 + 64) * 32 + c0) = b1;
        __syncthreads();
        frag_ab af[4], bfr[4];
#pragma unroll
        for (int i = 0; i < 4; i++) af[i] = *(const frag_ab*)(As + (wm + i * 16 + lr) * 32 + quad * 8);
#pragma unroll
        for (int j = 0; j < 4; j++) bfr[j] = *(const frag_ab*)(Bs + (wn + j * 16 + lr) * 32 + quad * 8);
#pragma unroll
        for (int i = 0; i < 4; i++)
#pragma unroll
            for (int j = 0; j < 4; j++)
                acc[i][j] = __builtin_amdgcn_mfma_f32_16x16x32_bf16(af[i], bfr[j], acc[i][j], 0, 0, 0);
    }
    // C/D layout: col = lane&15, row = (lane>>4)*4 + reg   [measured m89/m91]
#pragma unroll
    for (int i = 0; i < 4; i++)
#pragma unroll
        for (int j = 0; j < 4; j++)
#pragma unroll
            for (int r = 0; r < 4; r++) {
                long row = bm + wm + i * 16 + quad * 4 + r;
                long col = bn + wn + j * 16 + lr;
                C[row * N + col] = acc[i][j][r];
            }
}

// ---------------- RMSNorm(head_dim) + RoPE, fp32 in -> bf16 out [b][h][s][d] ----------------
__global__ __launch_bounds__(256) void rope_norm(const float* __restrict__ src, u16* __restrict__ dst,
                                                 const float* __restrict__ nw, int nh) {
    const int m = blockIdx.x;                 // 0..4095 (b*S+s)
    const int wave = threadIdx.x >> 6, lane = threadIdx.x & 63;
    const int s = m & (S_LEN - 1), b = m >> 11;
    const int d0 = 2 * lane;
    const float w0 = nw[d0], w1 = nw[d0 + 1];
    const int i0 = d0 & 63;
    const float lnt_over = 13.122363377404328f / 64.f;  // ln(500000)/64
    float inv0 = expf(-(float)i0 * lnt_over);
    float inv1 = expf(-(float)(i0 + 1) * lnt_over);
    float c0 = cosf((float)s * inv0), sn0 = sinf((float)s * inv0);
    float c1 = cosf((float)s * inv1), sn1 = sinf((float)s * inv1);
    for (int h = wave; h < nh; h += 4) {
        float2 x = *(const float2*)(src + (long)m * (nh * HD) + h * HD + d0);
        float ss = x.x * x.x + x.y * x.y;
#pragma unroll
        for (int off = 1; off < 64; off <<= 1) ss += __shfl_xor(ss, off);
        float rs = rsqrtf(ss * (1.f / HD) + 1e-5f);
        float xn0 = x.x * rs * w0;
        float xn1 = x.y * rs * w1;
        float p0 = __shfl_xor(xn0, 32);
        float p1 = __shfl_xor(xn1, 32);
        float r0 = (lane < 32) ? -p0 : p0;   // rotate_half
        float r1 = (lane < 32) ? -p1 : p1;
        float y0 = xn0 * c0 + r0 * sn0;
        float y1 = xn1 * c1 + r1 * sn1;
        unsigned outw = (unsigned)f2bf(y0) | ((unsigned)f2bf(y1) << 16);
        *(unsigned*)(dst + (((long)(b * nh + h) * S_LEN + s) * HD + d0)) = outw;
    }
}

// ---------------- V: fp32 [m][kh*128+d] -> bf16 TRANSPOSED [b][kh][d][s] ----------------
// LDS-tile transpose: 64 s-rows x 128 d per block.
__global__ __launch_bounds__(256) void pack_vt(const float* __restrict__ src, u16* __restrict__ dst) {
    __shared__ u16 t[128 * 72];  // [d][s], rows padded 64->72 (16B-aligned rows)
    const int tid = threadIdx.x;
    const int st = blockIdx.x & 31;
    const int kh = (blockIdx.x >> 5) & 3;
    const int b = blockIdx.x >> 7;
    const long m0 = (long)b * S_LEN + st * 64;
#pragma unroll
    for (int c = 0; c < 8; c++) {
        int idx = c * 256 + tid;           // 0..2047 float4s
        int r = idx >> 5, cg = idx & 31;   // s-row 0..63, col-group 0..31
        float4 v = *(const float4*)(src + (m0 + r) * (NKV * HD) + kh * HD + cg * 4);
        int col = cg * 4;
        t[(col + 0) * 72 + r] = f2bf(v.x);
        t[(col + 1) * 72 + r] = f2bf(v.y);
        t[(col + 2) * 72 + r] = f2bf(v.z);
        t[(col + 3) * 72 + r] = f2bf(v.w);
    }
    __syncthreads();
    const int d = tid >> 1, sh = (tid & 1) * 32;
    u16* dp = dst + ((long)(b * NKV + kh) * HD + d) * S_LEN + st * 64 + sh;
    const u16* tp = &t[d * 72 + sh];
    *(uint4*)(dp + 0)  = *(const uint4*)(tp + 0);
    *(uint4*)(dp + 8)  = *(const uint4*)(tp + 8);
    *(uint4*)(dp + 16) = *(const uint4*)(tp + 16);
    *(uint4*)(dp + 24) = *(const uint4*)(tp + 24);
}

// ---------------- MFMA flash attention ----------------
// Block = (b, h, 128-row Q tile); 4 waves x 32 Q rows; K-tile = 64 keys.
// K_lds [key][d] rows padded 136; V_lds [d][key] rows padded 72 (pre-transposed
// global Vt); P round-trips LDS per-wave (C-layout -> A-layout, m120 pattern).
__global__ __launch_bounds__(256, 2) void flash_attn(const u16* __restrict__ Q, const u16* __restrict__ K,
                                                     const u16* __restrict__ Vt, u16* __restrict__ O) {
    __shared__ u16 Kls[64 * 136];
    __shared__ u16 Vls[128 * 72];
    __shared__ u16 Pls[4 * 32 * 72];
    const int tid = threadIdx.x;
    const int wave = tid >> 6, lane = tid & 63;
    const int quad = lane >> 4, lr = lane & 15;
    const int qt = blockIdx.x & 15;
    const int h = (blockIdx.x >> 4) & 15;
    const int b = blockIdx.x >> 8;
    const int kh = h >> 2;
    const int q0 = qt * 128;
    const float scale = 0.08838834764831845f;  // 1/sqrt(128)
    const u16* Qb = Q + ((long)(b * NH + h) * S_LEN) * HD;
    const u16* Kb = K + ((long)(b * NKV + kh) * S_LEN) * HD;
    const u16* Vb = Vt + ((long)(b * NKV + kh) * HD) * S_LEN;

    // Q fragments held in registers for the whole kernel (A-layout: [m=lr][k])
    frag_ab qf[2][4];
#pragma unroll
    for (int mt = 0; mt < 2; mt++) {
        int qrow = q0 + wave * 32 + mt * 16 + lr;
#pragma unroll
        for (int ks = 0; ks < 4; ks++)
            qf[mt][ks] = *(const frag_ab*)(Qb + (long)qrow * HD + ks * 32 + quad * 8);
    }
    frag_cd oa[2][8];
    float m_i[2][4], l_i[2][4];
#pragma unroll
    for (int mt = 0; mt < 2; mt++) {
#pragma unroll
        for (int dt = 0; dt < 8; dt++) oa[mt][dt] = (frag_cd){0.f, 0.f, 0.f, 0.f};
#pragma unroll
        for (int r = 0; r < 4; r++) { m_i[mt][r] = -3e38f; l_i[mt][r] = 0.f; }
    }
    const int nkt = qt * 2 + 2;
    const int pbase = wave * 32 * 72;

    for (int kt = 0; kt < nkt; kt++) {
        const int j0 = kt * 64;
        __syncthreads();  // previous iteration's LDS readers done
#pragma unroll
        for (int c = 0; c < 4; c++) {
            int idx = c * 256 + tid;
            int row = idx >> 4, d0 = (idx & 15) * 8;
            *(uint4*)&Kls[row * 136 + d0] = *(const uint4*)(Kb + (long)(j0 + row) * HD + d0);
        }
#pragma unroll
        for (int c = 0; c < 4; c++) {
            int idx = c * 256 + tid;
            int d = idx >> 3, s0 = (idx & 7) * 8;
            *(uint4*)&Vls[d * 72 + s0] = *(const uint4*)(Vb + (long)d * S_LEN + j0 + s0);
        }
        __syncthreads();

        // S = Q K^T for this tile
        frag_cd sa[2][4];
#pragma unroll
        for (int mt = 0; mt < 2; mt++)
#pragma unroll
            for (int nt = 0; nt < 4; nt++) sa[mt][nt] = (frag_cd){0.f, 0.f, 0.f, 0.f};
#pragma unroll
        for (int nt = 0; nt < 4; nt++) {
            frag_ab kf[4];
#pragma unroll
            for (int ks = 0; ks < 4; ks++)
                kf[ks] = *(const frag_ab*)&Kls[(nt * 16 + lr) * 136 + ks * 32 + quad * 8];
#pragma unroll
            for (int mt = 0; mt < 2; mt++)
#pragma unroll
                for (int ks = 0; ks < 4; ks++)
                    sa[mt][nt] = __builtin_amdgcn_mfma_f32_16x16x32_bf16(qf[mt][ks], kf[ks], sa[mt][nt], 0, 0, 0);
        }

        // online softmax (C-layout: row = quad*4+r, col = lr)
#pragma unroll
        for (int mt = 0; mt < 2; mt++) {
            float mrow[4] = {-3e38f, -3e38f, -3e38f, -3e38f};
#pragma unroll
            for (int nt = 0; nt < 4; nt++) {
                int key = j0 + nt * 16 + lr;
#pragma unroll
                for (int r = 0; r < 4; r++) {
                    int qrow = q0 + wave * 32 + mt * 16 + quad * 4 + r;
                    float v = sa[mt][nt][r] * scale;
                    v = (key <= qrow) ? v : -3e38f;
                    sa[mt][nt][r] = v;
                    mrow[r] = fmaxf(mrow[r], v);
                }
            }
#pragma unroll
            for (int off = 1; off < 16; off <<= 1)
#pragma unroll
                for (int r = 0; r < 4; r++) mrow[r] = fmaxf(mrow[r], __shfl_xor(mrow[r], off));
            float rs[4];
#pragma unroll
            for (int r = 0; r < 4; r++) {
                float mn = fmaxf(m_i[mt][r], mrow[r]);
                float alpha = __expf(m_i[mt][r] - mn);
                m_i[mt][r] = mn;
                l_i[mt][r] *= alpha;
                rs[r] = 0.f;
#pragma unroll
                for (int dt = 0; dt < 8; dt++) oa[mt][dt][r] *= alpha;
            }
#pragma unroll
            for (int nt = 0; nt < 4; nt++)
#pragma unroll
                for (int r = 0; r < 4; r++) {
                    float p = __expf(sa[mt][nt][r] - m_i[mt][r]);
                    rs[r] += p;
                    Pls[pbase + (mt * 16 + quad * 4 + r) * 72 + nt * 16 + lr] = f2bf(p);
                }
#pragma unroll
            for (int off = 1; off < 16; off <<= 1)
#pragma unroll
                for (int r = 0; r < 4; r++) rs[r] += __shfl_xor(rs[r], off);
#pragma unroll
            for (int r = 0; r < 4; r++) l_i[mt][r] += rs[r];
        }

        // O += P V   (P via per-wave LDS round-trip; V already [d][key] in LDS)
#pragma unroll
        for (int ks = 0; ks < 2; ks++) {
            frag_ab pf[2];
#pragma unroll
            for (int mt = 0; mt < 2; mt++)
                pf[mt] = *(const frag_ab*)&Pls[pbase + (mt * 16 + lr) * 72 + ks * 32 + quad * 8];
#pragma unroll
            for (int dt = 0; dt < 8; dt++) {
                frag_ab vf = *(const frag_ab*)&Vls[(dt * 16 + lr) * 72 + ks * 32 + quad * 8];
                oa[0][dt] = __builtin_amdgcn_mfma_f32_16x16x32_bf16(pf[0], vf, oa[0][dt], 0, 0, 0);
                oa[1][dt] = __builtin_amdgcn_mfma_f32_16x16x32_bf16(pf[1], vf, oa[1][dt], 0, 0, 0);
            }
        }
    }

    // epilogue: O[b*S+s][h*128+d] bf16
#pragma unroll
    for (int mt = 0; mt < 2; mt++) {
        float inv[4];
#pragma unroll
        for (int r = 0; r < 4; r++) inv[r] = 1.f / l_i[mt][r];
#pragma unroll
        for (int dt = 0; dt < 8; dt++)
#pragma unroll
            for (int r = 0; r < 4; r++) {
                int s = q0 + wave * 32 + mt * 16 + quad * 4 + r;
                O[((long)b * S_LEN + s) * (NH * HD) + h * HD + dt * 16 + lr] =
                    f2bf(oa[mt][dt][r] * inv[r]);
            }
    }
}

extern "C" void kernel_launch(void* const* d_in, const int* in_sizes, int n_in,
                              void* d_out, int out_size, void* d_ws, size_t ws_size,
                              hipStream_t stream) {
    const float* hs  = (const float*)d_in[0];
    const float* q_w = (const float*)d_in[1];
    const float* k_w = (const float*)d_in[2];
    const float* v_w = (const float*)d_in[3];
    const float* o_w = (const float*)d_in[4];
    const float* qnw = (const float*)d_in[5];
    const float* knw = (const float*)d_in[6];
    float* out = (float*)d_out;

    // Workspace layout (72 MiB, live ranges stream-serialized & disjoint):
    //   [ 0,16M)  hs_bf : hidden bf16; reused as attn-out bf16
    //   [16,24M)  wbuf  : weights bf16 (reused per GEMM)
    //   [24,56M)  gout  : fp32 GEMM out (Q uses all 32M; K/V use [24,32M))
    //   [40,44M)  Kr    : bf16 [b][4][s][128]   (written after Q's gout dead)
    //   [44,48M)  Vt    : bf16 [b][4][d][s] TRANSPOSED
    //   [56,72M)  Qr    : bf16 [b][16][s][128]
    char* ws = (char*)d_ws;
    u16* hs_bf  = (u16*)(ws);
    u16* wbuf   = (u16*)(ws + (16ul << 20));
    float* gout = (float*)(ws + (24ul << 20));
    u16* Kr     = (u16*)(ws + (40ul << 20));
    u16* Vt     = (u16*)(ws + (44ul << 20));
    u16* Qr     = (u16*)(ws + (56ul << 20));
    (void)ws_size; (void)in_sizes; (void)n_in; (void)out_size;

    // hidden -> bf16
    conv_f32_bf16<<<(MROWS * HID / 4 + 255) / 256, 256, 0, stream>>>(hs, hs_bf, MROWS * HID / 4);

    // Q = hs @ q_w^T ; rmsnorm + rope
    conv_f32_bf16<<<(HID * HID / 4 + 255) / 256, 256, 0, stream>>>(q_w, wbuf, HID * HID / 4);
    dim3 gq(MROWS / 128, HID / 128);
    gemm_bt<<<gq, 256, 0, stream>>>(hs_bf, wbuf, gout, MROWS, HID, HID);
    rope_norm<<<MROWS, 256, 0, stream>>>(gout, Qr, qnw, NH);

    // K
    conv_f32_bf16<<<(NKV * HD * HID / 4 + 255) / 256, 256, 0, stream>>>(k_w, wbuf, NKV * HD * HID / 4);
    dim3 gk(MROWS / 128, (NKV * HD) / 128);
    gemm_bt<<<gk, 256, 0, stream>>>(hs_bf, wbuf, gout, MROWS, NKV * HD, HID);
    rope_norm<<<MROWS, 256, 0, stream>>>(gout, Kr, knw, NKV);

    // V (transposed pack)
    conv_f32_bf16<<<(NKV * HD * HID / 4 + 255) / 256, 256, 0, stream>>>(v_w, wbuf, NKV * HD * HID / 4);
    gemm_bt<<<gk, 256, 0, stream>>>(hs_bf, wbuf, gout, MROWS, NKV * HD, HID);
    pack_vt<<<BATCH * NKV * (S_LEN / 64), 256, 0, stream>>>(gout, Vt);

    // attention -> hs_bf (attn matrix [m][h*128+d] in bf16)
    flash_attn<<<(S_LEN / 128) * NH * BATCH, 256, 0, stream>>>(Qr, Kr, Vt, hs_bf);

    // out = attn @ o_w^T
    conv_f32_bf16<<<(HID * HID / 4 + 255) / 256, 256, 0, stream>>>(o_w, wbuf, HID * HID / 4);
    gemm_bt<<<gq, 256, 0, stream>>>(hs_bf, wbuf, out, MROWS, HID, HID);
}

// Round 4
// 506.342 us; speedup vs baseline: 9.9561x; 1.0874x over previous
//
#include <hip/hip_runtime.h>
#include <stdint.h>

#define S_LEN 2048
#define BATCH 2
#define NH 16
#define NKV 4
#define HD 128
#define HID 2048
#define MROWS (BATCH * S_LEN)  // 4096

typedef unsigned short u16;
typedef __attribute__((ext_vector_type(8))) short frag_ab;
typedef __attribute__((ext_vector_type(4))) float frag_cd;

static __device__ __forceinline__ float bf2f(u16 v) {
    union { unsigned u; float f; } t; t.u = ((unsigned)v) << 16; return t.f;
}
static __device__ __forceinline__ u16 f2bf(float f) {
    union { float f; unsigned u; } t; t.f = f;
    unsigned r = t.u + 0x7fffu + ((t.u >> 16) & 1u);  // RNE
    return (u16)(r >> 16);
}
// async global->LDS, 16B per lane; LDS dest = wave-uniform base + lane*16
static __device__ __forceinline__ void load_lds16(const u16* g, u16* l) {
    __builtin_amdgcn_global_load_lds((const __attribute__((address_space(1))) void*)g,
                                     (__attribute__((address_space(3))) void*)l, 16, 0, 0);
}

// ---------------- fp32 -> bf16 bulk convert ----------------
__global__ __launch_bounds__(256) void conv_f32_bf16(const float* __restrict__ src,
                                                     u16* __restrict__ dst, int n4) {
    int i = blockIdx.x * 256 + threadIdx.x;
    if (i >= n4) return;
    float4 v = ((const float4*)src)[i];
    ushort4 o;
    o.x = f2bf(v.x); o.y = f2bf(v.y); o.z = f2bf(v.z); o.w = f2bf(v.w);
    ((ushort4*)dst)[i] = o;
}

// ---------------- C = A (MxK) * B^T (B stored [N][K]), fp32 out ----------------
// 128x128 tile, 4 waves x (4x4) 16x16x32 MFMA, BK=32, global_load_lds width=16
// staging (m97 ladder step 3).
__global__ __launch_bounds__(256) void gemm_bt(const u16* __restrict__ A, const u16* __restrict__ B,
                                               float* __restrict__ C, int M, int N, int K) {
    __shared__ u16 As[128 * 32];
    __shared__ u16 Bs[128 * 32];
    const int tid = threadIdx.x;
    const int wave = tid >> 6, lane = tid & 63;
    const int quad = lane >> 4, lr = lane & 15;
    const int wm = (wave & 1) * 64, wn = (wave >> 1) * 64;
    const long bm = (long)blockIdx.x * 128, bn = (long)blockIdx.y * 128;
    // staging: chunk c = issue*256 + wave*64 + lane; row=c>>2, col16=c&3
    const int srow = (wave << 4) + (lane >> 2);   // + issue*64
    const int scol = (lane & 3) * 8;
    const u16* Ag = A + (bm + srow) * (long)K + scol;
    const u16* Bg = B + (bn + srow) * (long)K + scol;
    u16* AsW = As + wave * 512;                    // + issue*2048 (u16)
    u16* BsW = Bs + wave * 512;

    frag_cd acc[4][4];
#pragma unroll
    for (int i = 0; i < 4; i++)
#pragma unroll
        for (int j = 0; j < 4; j++) acc[i][j] = (frag_cd){0.f, 0.f, 0.f, 0.f};

    for (int k0 = 0; k0 < K; k0 += 32) {
        __syncthreads();  // prev iter's LDS readers done
        load_lds16(Ag + k0, AsW);
        load_lds16(Ag + (long)64 * K + k0, AsW + 2048);
        load_lds16(Bg + k0, BsW);
        load_lds16(Bg + (long)64 * K + k0, BsW + 2048);
        __syncthreads();  // staging complete (vmcnt(0) drained by barrier)
        frag_ab af[4], bfr[4];
#pragma unroll
        for (int i = 0; i < 4; i++) af[i] = *(const frag_ab*)(As + (wm + i * 16 + lr) * 32 + quad * 8);
#pragma unroll
        for (int j = 0; j < 4; j++) bfr[j] = *(const frag_ab*)(Bs + (wn + j * 16 + lr) * 32 + quad * 8);
#pragma unroll
        for (int i = 0; i < 4; i++)
#pragma unroll
            for (int j = 0; j < 4; j++)
                acc[i][j] = __builtin_amdgcn_mfma_f32_16x16x32_bf16(af[i], bfr[j], acc[i][j], 0, 0, 0);
    }
    // C/D layout: col = lane&15, row = (lane>>4)*4 + reg   [measured m89/m91]
#pragma unroll
    for (int i = 0; i < 4; i++)
#pragma unroll
        for (int j = 0; j < 4; j++)
#pragma unroll
            for (int r = 0; r < 4; r++) {
                long row = bm + wm + i * 16 + quad * 4 + r;
                long col = bn + wn + j * 16 + lr;
                C[row * N + col] = acc[i][j][r];
            }
}

// ---------------- RMSNorm(head_dim) + RoPE, fp32 in -> bf16 out [b][h][s][d] ----------------
__global__ __launch_bounds__(256) void rope_norm(const float* __restrict__ src, u16* __restrict__ dst,
                                                 const float* __restrict__ nw, int nh, int stride, int coff) {
    const int m = blockIdx.x;                 // 0..4095 (b*S+s)
    const int wave = threadIdx.x >> 6, lane = threadIdx.x & 63;
    const int s = m & (S_LEN - 1), b = m >> 11;
    const int d0 = 2 * lane;
    const float w0 = nw[d0], w1 = nw[d0 + 1];
    const int i0 = d0 & 63;
    const float lnt_over = 13.122363377404328f / 64.f;  // ln(500000)/64
    float inv0 = expf(-(float)i0 * lnt_over);
    float inv1 = expf(-(float)(i0 + 1) * lnt_over);
    float c0 = cosf((float)s * inv0), sn0 = sinf((float)s * inv0);
    float c1 = cosf((float)s * inv1), sn1 = sinf((float)s * inv1);
    for (int h = wave; h < nh; h += 4) {
        float2 x = *(const float2*)(src + (long)m * stride + coff + h * HD + d0);
        float ss = x.x * x.x + x.y * x.y;
#pragma unroll
        for (int off = 1; off < 64; off <<= 1) ss += __shfl_xor(ss, off);
        float rs = rsqrtf(ss * (1.f / HD) + 1e-5f);
        float xn0 = x.x * rs * w0;
        float xn1 = x.y * rs * w1;
        float p0 = __shfl_xor(xn0, 32);
        float p1 = __shfl_xor(xn1, 32);
        float r0 = (lane < 32) ? -p0 : p0;   // rotate_half
        float r1 = (lane < 32) ? -p1 : p1;
        float y0 = xn0 * c0 + r0 * sn0;
        float y1 = xn1 * c1 + r1 * sn1;
        unsigned outw = (unsigned)f2bf(y0) | ((unsigned)f2bf(y1) << 16);
        *(unsigned*)(dst + (((long)(b * nh + h) * S_LEN + s) * HD + d0)) = outw;
    }
}

// ---------------- V: fp32 gout [m][coff+kh*128+d] -> bf16 TRANSPOSED [b][kh][d][s] ----------------
__global__ __launch_bounds__(256) void pack_vt(const float* __restrict__ src, u16* __restrict__ dst,
                                               int stride, int coff) {
    __shared__ u16 t[128 * 72];  // [d][s], rows padded 64->72
    const int tid = threadIdx.x;
    const int st = blockIdx.x & 31;
    const int kh = (blockIdx.x >> 5) & 3;
    const int b = blockIdx.x >> 7;
    const long m0 = (long)b * S_LEN + st * 64;
#pragma unroll
    for (int c = 0; c < 8; c++) {
        int idx = c * 256 + tid;           // 0..2047 float4s
        int r = idx >> 5, cg = idx & 31;   // s-row 0..63, col-group 0..31
        float4 v = *(const float4*)(src + (m0 + r) * stride + coff + kh * HD + cg * 4);
        int col = cg * 4;
        t[(col + 0) * 72 + r] = f2bf(v.x);
        t[(col + 1) * 72 + r] = f2bf(v.y);
        t[(col + 2) * 72 + r] = f2bf(v.z);
        t[(col + 3) * 72 + r] = f2bf(v.w);
    }
    __syncthreads();
    const int d = tid >> 1, sh = (tid & 1) * 32;
    u16* dp = dst + ((long)(b * NKV + kh) * HD + d) * S_LEN + st * 64 + sh;
    const u16* tp = &t[d * 72 + sh];
    *(uint4*)(dp + 0)  = *(const uint4*)(tp + 0);
    *(uint4*)(dp + 8)  = *(const uint4*)(tp + 8);
    *(uint4*)(dp + 16) = *(const uint4*)(tp + 16);
    *(uint4*)(dp + 24) = *(const uint4*)(tp + 24);
}

// ---------------- MFMA flash attention v3 ----------------
// Causal-paired: block handles Q-tiles t=15-p then t=p (uniform 34 K-iters).
// No K/V LDS staging: kf/vf B-fragments read DIRECT from global (K[s][d],
// Vt[d][s] both 16B-contiguous in frag layout); L1/L2 broadcast across the 4
// waves. Only P's C->A layout round-trip uses LDS (per-wave region, stride 80
// u16 => 16B-aligned rows, no block barrier needed in the K-loop).
__global__ __launch_bounds__(256) void flash_attn(const u16* __restrict__ Q, const u16* __restrict__ K,
                                                  const u16* __restrict__ Vt, u16* __restrict__ O) {
    __shared__ u16 Pls[4 * 32 * 80];
    const int tid = threadIdx.x;
    const int wave = tid >> 6, lane = tid & 63;
    const int quad = lane >> 4, lr = lane & 15;
    const int p = blockIdx.x & 7;
    const int h = (blockIdx.x >> 3) & 15;
    const int b = blockIdx.x >> 7;
    const int kh = h >> 2;
    const float scale = 0.08838834764831845f;  // 1/sqrt(128)
    const u16* Qb = Q + ((long)(b * NH + h) * S_LEN) * HD;
    const u16* Kb = K + ((long)(b * NKV + kh) * S_LEN) * HD;
    const u16* Vb = Vt + ((long)(b * NKV + kh) * HD) * S_LEN;
    const int pbase = wave * 32 * 80;

    for (int ph = 0; ph < 2; ph++) {
        const int t = ph ? p : (15 - p);   // heavy tile first
        const int q0 = t * 128;
        frag_ab qf[2][4];
#pragma unroll
        for (int mt = 0; mt < 2; mt++) {
            int qrow = q0 + wave * 32 + mt * 16 + lr;
#pragma unroll
            for (int ks = 0; ks < 4; ks++)
                qf[mt][ks] = *(const frag_ab*)(Qb + (long)qrow * HD + ks * 32 + quad * 8);
        }
        frag_cd oa[2][8];
        float m_i[2][4], l_i[2][4];
#pragma unroll
        for (int mt = 0; mt < 2; mt++) {
#pragma unroll
            for (int dt = 0; dt < 8; dt++) oa[mt][dt] = (frag_cd){0.f, 0.f, 0.f, 0.f};
#pragma unroll
            for (int r = 0; r < 4; r++) { m_i[mt][r] = -3e38f; l_i[mt][r] = 0.f; }
        }
        const int nkt = 2 * t + 2;

        for (int kt = 0; kt < nkt; kt++) {
            const int j0 = kt * 64;
            // S = Q K^T  (kf direct from global K[key][d])
            frag_cd sa[2][4];
#pragma unroll
            for (int mt = 0; mt < 2; mt++)
#pragma unroll
                for (int nt = 0; nt < 4; nt++) sa[mt][nt] = (frag_cd){0.f, 0.f, 0.f, 0.f};
#pragma unroll
            for (int nt = 0; nt < 4; nt++) {
                frag_ab kf[4];
#pragma unroll
                for (int ks = 0; ks < 4; ks++)
                    kf[ks] = *(const frag_ab*)(Kb + (long)(j0 + nt * 16 + lr) * HD + ks * 32 + quad * 8);
#pragma unroll
                for (int mt = 0; mt < 2; mt++)
#pragma unroll
                    for (int ks = 0; ks < 4; ks++)
                        sa[mt][nt] = __builtin_amdgcn_mfma_f32_16x16x32_bf16(qf[mt][ks], kf[ks], sa[mt][nt], 0, 0, 0);
            }

            const bool need_mask = (j0 + 63) > (q0 + wave * 32);
            // online softmax (C-layout: row=quad*4+r, col=lr)
#pragma unroll
            for (int mt = 0; mt < 2; mt++) {
                float mrow[4] = {-3e38f, -3e38f, -3e38f, -3e38f};
#pragma unroll
                for (int nt = 0; nt < 4; nt++) {
                    int key = j0 + nt * 16 + lr;
#pragma unroll
                    for (int r = 0; r < 4; r++) {
                        int qrow = q0 + wave * 32 + mt * 16 + quad * 4 + r;
                        float v = sa[mt][nt][r] * scale;
                        if (need_mask) v = (key <= qrow) ? v : -3e38f;
                        sa[mt][nt][r] = v;
                        mrow[r] = fmaxf(mrow[r], v);
                    }
                }
#pragma unroll
                for (int off = 1; off < 16; off <<= 1)
#pragma unroll
                    for (int r = 0; r < 4; r++) mrow[r] = fmaxf(mrow[r], __shfl_xor(mrow[r], off));
                float rs[4];
#pragma unroll
                for (int r = 0; r < 4; r++) {
                    float mn = fmaxf(m_i[mt][r], mrow[r]);
                    float alpha = __expf(m_i[mt][r] - mn);
                    m_i[mt][r] = mn;
                    l_i[mt][r] *= alpha;
                    rs[r] = 0.f;
#pragma unroll
                    for (int dt = 0; dt < 8; dt++) oa[mt][dt][r] *= alpha;
                }
#pragma unroll
                for (int nt = 0; nt < 4; nt++)
#pragma unroll
                    for (int r = 0; r < 4; r++) {
                        float pw = __expf(sa[mt][nt][r] - m_i[mt][r]);
                        rs[r] += pw;
                        Pls[pbase + (mt * 16 + quad * 4 + r) * 80 + nt * 16 + lr] = f2bf(pw);
                    }
#pragma unroll
                for (int off = 1; off < 16; off <<= 1)
#pragma unroll
                    for (int r = 0; r < 4; r++) rs[r] += __shfl_xor(rs[r], off);
#pragma unroll
                for (int r = 0; r < 4; r++) l_i[mt][r] += rs[r];
            }

            // O += P V  (pf via per-wave LDS; vf direct from global Vt[d][s])
#pragma unroll
            for (int ks = 0; ks < 2; ks++) {
                frag_ab pf[2];
#pragma unroll
                for (int mt = 0; mt < 2; mt++)
                    pf[mt] = *(const frag_ab*)&Pls[pbase + (mt * 16 + lr) * 80 + ks * 32 + quad * 8];
                frag_ab vf[8];
#pragma unroll
                for (int dt = 0; dt < 8; dt++)
                    vf[dt] = *(const frag_ab*)(Vb + (long)(dt * 16 + lr) * S_LEN + j0 + ks * 32 + quad * 8);
#pragma unroll
                for (int dt = 0; dt < 8; dt++) {
                    oa[0][dt] = __builtin_amdgcn_mfma_f32_16x16x32_bf16(pf[0], vf[dt], oa[0][dt], 0, 0, 0);
                    oa[1][dt] = __builtin_amdgcn_mfma_f32_16x16x32_bf16(pf[1], vf[dt], oa[1][dt], 0, 0, 0);
                }
            }
        }

        // epilogue: O[b*S+s][h*128+d] bf16
#pragma unroll
        for (int mt = 0; mt < 2; mt++) {
            float inv[4];
#pragma unroll
            for (int r = 0; r < 4; r++) inv[r] = 1.f / l_i[mt][r];
#pragma unroll
            for (int dt = 0; dt < 8; dt++)
#pragma unroll
                for (int r = 0; r < 4; r++) {
                    int s = q0 + wave * 32 + mt * 16 + quad * 4 + r;
                    O[((long)b * S_LEN + s) * (NH * HD) + h * HD + dt * 16 + lr] =
                        f2bf(oa[mt][dt][r] * inv[r]);
                }
        }
    }
}

extern "C" void kernel_launch(void* const* d_in, const int* in_sizes, int n_in,
                              void* d_out, int out_size, void* d_ws, size_t ws_size,
                              hipStream_t stream) {
    const float* hs  = (const float*)d_in[0];
    const float* q_w = (const float*)d_in[1];
    const float* k_w = (const float*)d_in[2];
    const float* v_w = (const float*)d_in[3];
    const float* o_w = (const float*)d_in[4];
    const float* qnw = (const float*)d_in[5];
    const float* knw = (const float*)d_in[6];
    float* out = (float*)d_out;

    // Workspace (72 MiB, live ranges stream-serialized & disjoint):
    //   [ 0,16M) hs_bf : hidden bf16; later attn-out bf16
    //   [16,24M) wbuf  : weights bf16 (Q 8M; then KV 4M; then O 8M)
    //   [24,56M) gout  : fp32 GEMM out (Q all 32M; KV uses [24,40) only)
    //   [40,44M) Kr    : bf16 [b][4][s][128]
    //   [44,48M) Vt    : bf16 [b][4][d][s] transposed
    //   [56,72M) Qr    : bf16 [b][16][s][128]
    char* ws = (char*)d_ws;
    u16* hs_bf  = (u16*)(ws);
    u16* wbuf   = (u16*)(ws + (16ul << 20));
    float* gout = (float*)(ws + (24ul << 20));
    u16* Kr     = (u16*)(ws + (40ul << 20));
    u16* Vt     = (u16*)(ws + (44ul << 20));
    u16* Qr     = (u16*)(ws + (56ul << 20));
    (void)ws_size; (void)in_sizes; (void)n_in; (void)out_size;

    // hidden -> bf16
    conv_f32_bf16<<<(MROWS * HID / 4 + 255) / 256, 256, 0, stream>>>(hs, hs_bf, MROWS * HID / 4);

    // Q = hs @ q_w^T ; rmsnorm + rope
    conv_f32_bf16<<<(HID * HID / 4 + 255) / 256, 256, 0, stream>>>(q_w, wbuf, HID * HID / 4);
    dim3 gq(MROWS / 128, HID / 128);
    gemm_bt<<<gq, 256, 0, stream>>>(hs_bf, wbuf, gout, MROWS, HID, HID);
    rope_norm<<<MROWS, 256, 0, stream>>>(gout, Qr, qnw, NH, HID, 0);

    // K|V fused projection: wbuf rows [0,512)=k_w, [512,1024)=v_w; N=1024
    conv_f32_bf16<<<(NKV * HD * HID / 4 + 255) / 256, 256, 0, stream>>>(k_w, wbuf, NKV * HD * HID / 4);
    conv_f32_bf16<<<(NKV * HD * HID / 4 + 255) / 256, 256, 0, stream>>>(v_w, wbuf + NKV * HD * HID, NKV * HD * HID / 4);
    dim3 gkv(MROWS / 128, (2 * NKV * HD) / 128);
    gemm_bt<<<gkv, 256, 0, stream>>>(hs_bf, wbuf, gout, MROWS, 2 * NKV * HD, HID);
    rope_norm<<<MROWS, 256, 0, stream>>>(gout, Kr, knw, NKV, 2 * NKV * HD, 0);
    pack_vt<<<BATCH * NKV * (S_LEN / 64), 256, 0, stream>>>(gout, Vt, 2 * NKV * HD, NKV * HD);

    // attention -> hs_bf
    flash_attn<<<8 * NH * BATCH, 256, 0, stream>>>(Qr, Kr, Vt, hs_bf);

    // out = attn @ o_w^T
    conv_f32_bf16<<<(HID * HID / 4 + 255) / 256, 256, 0, stream>>>(o_w, wbuf, HID * HID / 4);
    gemm_bt<<<gq, 256, 0, stream>>>(hs_bf, wbuf, out, MROWS, HID, HID);
}